// Round 1
// 887.753 us; speedup vs baseline: 1.1192x; 1.1192x over previous
//
#include <hip/hip_runtime.h>
#include <hip/hip_bf16.h>
#include <math.h>

#define HIDDEN 7168
#define NH 32
#define DQ 1536
#define DKV 512
#define DH 128
#define DR 64
#define SEQ 2048
#define DKVP 640        // DKV+DR=576 padded to multiple of 128
#define NQKV 2176       // DQ + DKVP (fused down-proj width), 17*128

typedef unsigned short u16;
typedef __bf16 bf16_t;
typedef bf16_t bf16x8 __attribute__((ext_vector_type(8)));
typedef float f32x4 __attribute__((ext_vector_type(4)));

__device__ __forceinline__ float bf2f(u16 h) {
    union { unsigned u; float f; } q; q.u = ((unsigned)h) << 16; return q.f;
}
__device__ __forceinline__ u16 f2bf(float x) {
    union { float f; unsigned u; } q; q.f = x;
    unsigned r = q.u + 0x7fffu + ((q.u >> 16) & 1u);   // round-to-nearest-even
    return (u16)(r >> 16);
}

// ---------------------------------------------------------------------------
// Legacy 128x128 GEMM (kept for the down-projection: N=2176 not 256-divisible,
// and its 272-block grid fills CUs better than 72 big blocks would).
// C[M,N] = A[M,K](bf16,lda) @ B^T where BT[N,K](ldb).
// ---------------------------------------------------------------------------
template <typename CT>
__global__ __launch_bounds__(256) void gemm_bt(
    const u16* __restrict__ A, const u16* __restrict__ B, CT* __restrict__ C,
    int K, int lda, int ldb, int ldc, long sA, long sB, long sC)
{
    __shared__ u16 As[128 * 32];
    __shared__ u16 Bs[128 * 32];
    A += (long)blockIdx.z * sA;
    B += (long)blockIdx.z * sB;
    C += (long)blockIdx.z * sC;

    const int t = threadIdx.x;
    const int w = t >> 6, lane = t & 63;
    const int lane15 = lane & 15, quad = lane >> 4;
    const int brow = blockIdx.y * 128, bcol = blockIdx.x * 128;
    const int wrow = (w >> 1) * 64, wcol = (w & 1) * 64;

    f32x4 acc[4][4] = {};

    for (int k0 = 0; k0 < K; k0 += 32) {
#pragma unroll
        for (int i = 0; i < 2; ++i) {
            int chunk = i * 256 + t;
            int row = chunk >> 2;
            int kc = (chunk & 3) * 8;
            const u16* ga = A + (long)(brow + row) * lda + k0 + kc;
            const u16* gb = B + (long)(bcol + row) * ldb + k0 + kc;
            u16* la = As + (i * 256 + w * 64) * 8;
            u16* lb = Bs + (i * 256 + w * 64) * 8;
            __builtin_amdgcn_global_load_lds(
                (const __attribute__((address_space(1))) void*)ga,
                (__attribute__((address_space(3))) void*)la, 16, 0, 0);
            __builtin_amdgcn_global_load_lds(
                (const __attribute__((address_space(1))) void*)gb,
                (__attribute__((address_space(3))) void*)lb, 16, 0, 0);
        }
        __syncthreads();

        bf16x8 af[4], bfr[4];
#pragma unroll
        for (int mi = 0; mi < 4; ++mi)
            af[mi] = *(const bf16x8*)(As + (wrow + mi * 16 + lane15) * 32 + quad * 8);
#pragma unroll
        for (int ni = 0; ni < 4; ++ni)
            bfr[ni] = *(const bf16x8*)(Bs + (wcol + ni * 16 + lane15) * 32 + quad * 8);
#pragma unroll
        for (int mi = 0; mi < 4; ++mi)
#pragma unroll
            for (int ni = 0; ni < 4; ++ni)
                acc[mi][ni] = __builtin_amdgcn_mfma_f32_16x16x32_bf16(
                    af[mi], bfr[ni], acc[mi][ni], 0, 0, 0);
        __syncthreads();
    }

#pragma unroll
    for (int mi = 0; mi < 4; ++mi) {
#pragma unroll
        for (int ni = 0; ni < 4; ++ni) {
            int r0 = brow + wrow + mi * 16 + quad * 4;
            int cc = bcol + wcol + ni * 16 + lane15;
#pragma unroll
            for (int r = 0; r < 4; ++r) {
                float v = acc[mi][ni][r];
                if constexpr (sizeof(CT) == 2) C[(long)(r0 + r) * ldc + cc] = f2bf(v);
                else                           C[(long)(r0 + r) * ldc + cc] = v;
            }
        }
    }
}

// ---------------------------------------------------------------------------
// 256x256 deep-pipelined GEMM (T1+T3+T4+T5).  BK=32, 8 waves (2Mx4N),
// per-wave 128x64 output.  LDS = ring of 4 K-tile slots (A 16KB + B 16KB each)
// = 128 KiB -> 1 block/CU, 8 waves.  Staging runs 3 K-tiles ahead with
// counted s_waitcnt vmcnt(8) (never 0 in steady state); raw s_barrier only
// (no __syncthreads vmcnt(0) drain).  BK=32 gives 64-B LDS rows, so the
// fragment ds_read_b128 pattern (row=lane15, k=quad*8) covers all 8
// bank-groups uniformly: conflict-free with LINEAR layout -> global_load_lds
// needs no source swizzle (rule #21 trivially satisfied).
// Requires: M%256==0, N%256==0, K%32==0, K/32>=4, grid = (M/256)*(N/256).
// ---------------------------------------------------------------------------
template <typename CT>
__global__ __launch_bounds__(512, 2) void gemm256(
    const u16* __restrict__ A, const u16* __restrict__ B, CT* __restrict__ C,
    int K, int lda, int ldb, int ldc, int nx)
{
    __shared__ u16 lds[4 * 16384];    // 128 KiB: 4 slots of [A 8192 u16][B 8192 u16]
    const int t = threadIdx.x;
    const int lane = t & 63;
    const int w = t >> 6;
    const int lane15 = lane & 15, quad = lane >> 4;
    const int wm = w >> 2, wn = w & 3;            // 2 x 4 wave grid

    // T1: bijective XCD swizzle (nwg % 8 == 0 for all call sites).
    int nwg = gridDim.x, wg = blockIdx.x, tile = wg;
    if ((nwg & 7) == 0) { int q = nwg >> 3; tile = (wg & 7) * q + (wg >> 3); }
    const int bx = tile % nx, by = tile / nx;
    const long brow = (long)by * 256, bcol = (long)bx * 256;

    // Per-thread staging sources: chunk c covers (row = c>>2, k8 = (c&3)*8).
    const u16* gsrc[4];
    int loff[4];
#pragma unroll
    for (int j = 0; j < 2; ++j) {
        int c = j * 512 + t;
        int row = c >> 2, k8 = (c & 3) * 8;
        gsrc[j]     = A + (brow + row) * lda + k8;
        gsrc[j + 2] = B + (bcol + row) * ldb + k8;
        loff[j]     = c * 8;              // u16 units inside slot (A region)
        loff[j + 2] = 8192 + c * 8;       // B region
    }

    const int NT = K >> 5;
    auto stage = [&](int tt) {            // 4 x global_load_lds(16B) per thread
        u16* sb = lds + (tt & 3) * 16384;
        int ko = tt * 32;
#pragma unroll
        for (int j = 0; j < 4; ++j)
            __builtin_amdgcn_global_load_lds(
                (const __attribute__((address_space(1))) void*)(gsrc[j] + ko),
                (__attribute__((address_space(3))) void*)(sb + loff[j]), 16, 0, 0);
    };

    f32x4 acc[8][4] = {};
    const int aoff = (wm * 128 + lane15) * 32 + quad * 8;
    const int boff = 8192 + (wn * 64 + lane15) * 32 + quad * 8;

    stage(0); stage(1); stage(2);         // prime ring: 12 loads in flight

    for (int T = 0; T < NT; ++T) {
        // counted wait: tiles T+1,T+2 (8 loads) stay in flight; 0 only at tail
        int rem = NT - 1 - T;
        if (rem >= 2)      asm volatile("s_waitcnt vmcnt(8)" ::: "memory");
        else if (rem == 1) asm volatile("s_waitcnt vmcnt(4)" ::: "memory");
        else               asm volatile("s_waitcnt vmcnt(0)" ::: "memory");
        __builtin_amdgcn_s_barrier();                 // tile T visible to all waves
        __builtin_amdgcn_sched_barrier(0);
        if (T + 3 < NT) stage(T + 3);                 // overwrites slot read in T-1

        const u16* sb = lds + (T & 3) * 16384;
        bf16x8 bfr[4], af[8];
#pragma unroll
        for (int ni = 0; ni < 4; ++ni)
            bfr[ni] = *(const bf16x8*)(sb + boff + ni * 512);
#pragma unroll
        for (int mi = 0; mi < 4; ++mi)
            af[mi] = *(const bf16x8*)(sb + aoff + mi * 512);
        __builtin_amdgcn_s_setprio(1);
#pragma unroll
        for (int mi = 0; mi < 4; ++mi)
#pragma unroll
            for (int ni = 0; ni < 4; ++ni)
                acc[mi][ni] = __builtin_amdgcn_mfma_f32_16x16x32_bf16(
                    af[mi], bfr[ni], acc[mi][ni], 0, 0, 0);
        __builtin_amdgcn_s_setprio(0);
#pragma unroll
        for (int mi = 4; mi < 8; ++mi)
            af[mi] = *(const bf16x8*)(sb + aoff + mi * 512);
        __builtin_amdgcn_s_setprio(1);
#pragma unroll
        for (int mi = 4; mi < 8; ++mi)
#pragma unroll
            for (int ni = 0; ni < 4; ++ni)
                acc[mi][ni] = __builtin_amdgcn_mfma_f32_16x16x32_bf16(
                    af[mi], bfr[ni], acc[mi][ni], 0, 0, 0);
        __builtin_amdgcn_s_setprio(0);
        // drain LDS reads before next iter's barrier (slot reuse safety)
        asm volatile("s_waitcnt lgkmcnt(0)" ::: "memory");
        __builtin_amdgcn_sched_barrier(0);
    }

    const long crow0 = brow + wm * 128 + quad * 4;
    const long ccol0 = bcol + wn * 64 + lane15;
#pragma unroll
    for (int mi = 0; mi < 8; ++mi) {
#pragma unroll
        for (int ni = 0; ni < 4; ++ni) {
            long r0 = crow0 + mi * 16;
            long cc = ccol0 + ni * 16;
#pragma unroll
            for (int r = 0; r < 4; ++r) {
                float v = acc[mi][ni][r];
                if constexpr (sizeof(CT) == 2) C[(r0 + r) * ldc + cc] = f2bf(v);
                else                           C[(r0 + r) * ldc + cc] = v;
            }
        }
    }
}

// ---------------------------------------------------------------------------
// Fused flash attention, v2 (transposed-S + register prefetch). Unchanged.
// ---------------------------------------------------------------------------
__global__ __launch_bounds__(256, 2) void flash_attn(
    const u16* __restrict__ qb, const u16* __restrict__ kb,
    const u16* __restrict__ vT, u16* __restrict__ ob, float scale)
{
    __shared__ u16 Ks[64 * 200];      // 25.6 KB
    __shared__ u16 Vs[128 * 72];      // 18.4 KB
    __shared__ u16 Ps[4 * 32 * 72];   // 18.4 KB, wave-private [32 q][72]

    const int t = threadIdx.x;
    const int w = t >> 6, lane = t & 63;
    const int lane15 = lane & 15, quad = lane >> 4;
    const int h = blockIdx.y;
    const int q0 = blockIdx.x * 128 + w * 32;
    u16* Psw = Ps + w * 32 * 72;

    bf16x8 Qf[2][6];
#pragma unroll
    for (int qt = 0; qt < 2; ++qt)
#pragma unroll
        for (int kc = 0; kc < 6; ++kc)
            Qf[qt][kc] = *(const bf16x8*)(
                qb + (long)(h * SEQ + q0 + qt * 16 + lane15) * 192 + kc * 32 + quad * 8);

    f32x4 O[8][2] = {};
    float mst[2] = { -3.0e38f, -3.0e38f }, lst[2] = { 0.f, 0.f };

    bf16x8 Kpf[6], Vpf[4];
    auto load_tiles = [&](int kt) {
#pragma unroll
        for (int i = 0; i < 6; ++i) {
            int chunk = i * 256 + t;
            int row = chunk / 24, c8 = (chunk % 24) * 8;
            Kpf[i] = *(const bf16x8*)(kb + (long)(h * SEQ + kt * 64 + row) * 192 + c8);
        }
#pragma unroll
        for (int i = 0; i < 4; ++i) {
            int chunk = i * 256 + t;
            int dh = chunk >> 3, c8 = (chunk & 7) * 8;
            Vpf[i] = *(const bf16x8*)(vT + (long)(h * 128 + dh) * SEQ + kt * 64 + c8);
        }
    };
    auto store_tiles = [&]() {
#pragma unroll
        for (int i = 0; i < 6; ++i) {
            int chunk = i * 256 + t;
            int row = chunk / 24, c8 = (chunk % 24) * 8;
            *(bf16x8*)(Ks + row * 200 + c8) = Kpf[i];
        }
#pragma unroll
        for (int i = 0; i < 4; ++i) {
            int chunk = i * 256 + t;
            int dh = chunk >> 3, c8 = (chunk & 7) * 8;
            *(bf16x8*)(Vs + dh * 72 + c8) = Vpf[i];
        }
    };

    load_tiles(0);
    store_tiles();
    __syncthreads();

    for (int kt = 0; kt < SEQ / 64; ++kt) {
        load_tiles(kt + 1 < SEQ / 64 ? kt + 1 : kt);

        f32x4 St[4][2] = {};
#pragma unroll
        for (int kc = 0; kc < 6; ++kc) {
            bf16x8 Kf[4];
#pragma unroll
            for (int k4 = 0; k4 < 4; ++k4)
                Kf[k4] = *(const bf16x8*)(Ks + (k4 * 16 + lane15) * 200 + kc * 32 + quad * 8);
#pragma unroll
            for (int k4 = 0; k4 < 4; ++k4)
#pragma unroll
                for (int qt = 0; qt < 2; ++qt)
                    St[k4][qt] = __builtin_amdgcn_mfma_f32_16x16x32_bf16(
                        Kf[k4], Qf[qt][kc], St[k4][qt], 0, 0, 0);
        }

#pragma unroll
        for (int qt = 0; qt < 2; ++qt) {
            float rm = St[0][qt][0];
#pragma unroll
            for (int k4 = 0; k4 < 4; ++k4)
#pragma unroll
                for (int r = 0; r < 4; ++r) rm = fmaxf(rm, St[k4][qt][r]);
            rm = fmaxf(rm, __shfl_xor(rm, 16, 64));
            rm = fmaxf(rm, __shfl_xor(rm, 32, 64));
            rm *= scale;
            float mnew = fmaxf(mst[qt], rm);
            float alpha = __expf(mst[qt] - mnew);
            mst[qt] = mnew;
            float rs = 0.f;
#pragma unroll
            for (int k4 = 0; k4 < 4; ++k4)
#pragma unroll
                for (int r = 0; r < 4; ++r) {
                    float pv = __expf(St[k4][qt][r] * scale - mnew);
                    St[k4][qt][r] = pv; rs += pv;
                }
            rs += __shfl_xor(rs, 16, 64);
            rs += __shfl_xor(rs, 32, 64);
            lst[qt] = lst[qt] * alpha + rs;
#pragma unroll
            for (int dt = 0; dt < 8; ++dt)
#pragma unroll
                for (int r = 0; r < 4; ++r) O[dt][qt][r] *= alpha;
        }

#pragma unroll
        for (int qt = 0; qt < 2; ++qt)
#pragma unroll
            for (int k4 = 0; k4 < 4; ++k4) {
                ushort4 pk;
                pk.x = f2bf(St[k4][qt][0]); pk.y = f2bf(St[k4][qt][1]);
                pk.z = f2bf(St[k4][qt][2]); pk.w = f2bf(St[k4][qt][3]);
                *(ushort4*)(Psw + (qt * 16 + lane15) * 72 + k4 * 16 + quad * 4) = pk;
            }

#pragma unroll
        for (int kc2 = 0; kc2 < 2; ++kc2) {
            bf16x8 Pf[2], Vf[8];
#pragma unroll
            for (int qt = 0; qt < 2; ++qt)
                Pf[qt] = *(const bf16x8*)(Psw + (qt * 16 + lane15) * 72 + kc2 * 32 + quad * 8);
#pragma unroll
            for (int dt = 0; dt < 8; ++dt)
                Vf[dt] = *(const bf16x8*)(Vs + (dt * 16 + lane15) * 72 + kc2 * 32 + quad * 8);
#pragma unroll
            for (int dt = 0; dt < 8; ++dt)
#pragma unroll
                for (int qt = 0; qt < 2; ++qt)
                    O[dt][qt] = __builtin_amdgcn_mfma_f32_16x16x32_bf16(
                        Vf[dt], Pf[qt], O[dt][qt], 0, 0, 0);
        }
        __syncthreads();
        store_tiles();
        __syncthreads();
    }

#pragma unroll
    for (int qt = 0; qt < 2; ++qt) {
        float inv = 1.f / lst[qt];
        int s = q0 + qt * 16 + lane15;
#pragma unroll
        for (int dt = 0; dt < 8; ++dt) {
            ushort4 ov;
            ov.x = f2bf(O[dt][qt][0] * inv); ov.y = f2bf(O[dt][qt][1] * inv);
            ov.z = f2bf(O[dt][qt][2] * inv); ov.w = f2bf(O[dt][qt][3] * inv);
            *(ushort4*)(ob + (long)s * 4096 + h * 128 + dt * 16 + quad * 4) = ov;
        }
    }
}

// ---------------------------------------------------------------------------
__global__ void cast_bf16_k(const float* __restrict__ in, u16* __restrict__ out, long n)
{
    long i = ((long)blockIdx.x * 256 + threadIdx.x) * 4;
    if (i >= n) return;
    float4 v = *(const float4*)(in + i);
    ushort4 o;
    o.x = f2bf(v.x); o.y = f2bf(v.y); o.z = f2bf(v.z); o.w = f2bf(v.w);
    *(ushort4*)(out + i) = o;
}

__global__ void transpose_cast(const float* __restrict__ in, u16* __restrict__ out,
                               int K, int N, int Npad)
{
    __shared__ float tile[32][33];
    int n0 = blockIdx.x * 32, k0 = blockIdx.y * 32;
    int tx = threadIdx.x, ty = threadIdx.y;
#pragma unroll
    for (int i = 0; i < 32; i += 8) {
        int k = k0 + ty + i, n = n0 + tx;
        tile[ty + i][tx] = (n < N) ? in[(long)k * N + n] : 0.f;
    }
    __syncthreads();
#pragma unroll
    for (int i = 0; i < 32; i += 8) {
        int n = n0 + ty + i, k = k0 + tx;
        out[(long)n * K + k] = f2bf(tile[tx][ty + i]);
    }
}

__global__ __launch_bounds__(256) void rmsnorm_k(
    const u16* __restrict__ in, const float* __restrict__ g,
    u16* __restrict__ out, int C, int ldin)
{
    const int row = blockIdx.x;
    const u16* x = in + (long)row * ldin;
    float ss = 0.f;
    for (int c = threadIdx.x; c < C; c += 256) { float v = bf2f(x[c]); ss += v * v; }
#pragma unroll
    for (int off = 32; off; off >>= 1) ss += __shfl_down(ss, off, 64);
    __shared__ float red[4];
    if ((threadIdx.x & 63) == 0) red[threadIdx.x >> 6] = ss;
    __syncthreads();
    float tot = red[0] + red[1] + red[2] + red[3];
    float r = rsqrtf(tot / (float)C + 1.1920929e-07f);
    for (int c = threadIdx.x; c < C; c += 256)
        out[(long)row * C + c] = f2bf(bf2f(x[c]) * r * g[c]);
}

// ---------------------------------------------------------------------------
__global__ void rope_tab_k(float* __restrict__ ct, float* __restrict__ st)
{
    int idx = blockIdx.x * 256 + threadIdx.x;   // SEQ*32 total
    int s = idx >> 5, j = idx & 31;
    float invf = powf(10000.f, -(float)(2 * j) / 64.f);
    float fr = (float)s * invf;
    float sn, cs; sincosf(fr, &sn, &cs);
    ct[idx] = cs; st[idx] = sn;
}

__device__ __forceinline__ float rope_val(const u16* src, int i, int s,
                                          const float* ct, const float* st)
{
    int j = i & 31;
    float cs = ct[s * 32 + j], sn = st[s * 32 + j];
    float x = bf2f(src[i]);
    float xo = (i < 32) ? bf2f(src[i + 32]) : bf2f(src[i - 32]);
    return (i < 32) ? (x * cs - xo * sn) : (x * cs + xo * sn);
}

__global__ void build_q_k(const u16* __restrict__ qcr, u16* __restrict__ q,
                          const float* __restrict__ ct, const float* __restrict__ st)
{
    int s = blockIdx.x, h = blockIdx.y, d = threadIdx.x;
    const u16* src = qcr + ((long)s * NH + h) * 192;
    float val = (d < 128) ? bf2f(src[d]) : rope_val(src + 128, d - 128, s, ct, st);
    q[((long)h * SEQ + s) * 192 + d] = f2bf(val);
}

__global__ void build_k_k(const u16* __restrict__ kv, const u16* __restrict__ ropebuf,
                          int ldrope, u16* __restrict__ kbuf,
                          const float* __restrict__ ct, const float* __restrict__ st)
{
    int s = blockIdx.x, h = blockIdx.y, d = threadIdx.x;
    float val = (d < 128) ? bf2f(kv[(long)s * 8192 + h * 256 + d])
                          : rope_val(ropebuf + (long)s * ldrope, d - 128, s, ct, st);
    kbuf[((long)h * SEQ + s) * 192 + d] = f2bf(val);
}

__global__ void build_vT_k(const u16* __restrict__ kv, u16* __restrict__ vT)
{
    __shared__ u16 tile[32][33];
    int s0 = blockIdx.x * 32, d0 = blockIdx.y * 32, h = blockIdx.z;
    int tx = threadIdx.x, ty = threadIdx.y;
#pragma unroll
    for (int i = 0; i < 32; i += 8)
        tile[ty + i][tx] = kv[(long)(s0 + ty + i) * 8192 + h * 256 + 128 + d0 + tx];
    __syncthreads();
#pragma unroll
    for (int i = 0; i < 32; i += 8)
        vT[((long)h * 128 + d0 + ty + i) * SEQ + s0 + tx] = tile[tx][ty + i];
}

// ---------------------------------------------------------------------------
extern "C" void kernel_launch(void* const* d_in, const int* in_sizes, int n_in,
                              void* d_out, int out_size, void* d_ws, size_t ws_size,
                              hipStream_t stream)
{
    const float* hidden = (const float*)d_in[0];
    const float* W_dq   = (const float*)d_in[1];
    const float* g_q    = (const float*)d_in[2];
    const float* W_uq   = (const float*)d_in[3];
    const float* W_dkv  = (const float*)d_in[4];
    const float* g_kv   = (const float*)d_in[5];
    const float* W_ukv  = (const float*)d_in[6];
    const float* W_o    = (const float*)d_in[7];
    float* out = (float*)d_out;

    char* p = (char*)d_ws;
    auto alloc = [&](size_t bytes) {
        char* r = p; p += (bytes + 255) & ~(size_t)255; return r;
    };
    u16* hbf   = (u16*)alloc((size_t)SEQ * HIDDEN * 2);
    u16* WTqkv = (u16*)alloc((size_t)NQKV * HIDDEN * 2);
    u16* WTuq  = (u16*)alloc((size_t)6144 * DQ * 2);
    u16* WTukv = (u16*)alloc((size_t)8192 * DKV * 2);
    u16* WTo   = (u16*)alloc((size_t)HIDDEN * 4096 * 2);
    u16* cqc   = (u16*)alloc((size_t)SEQ * NQKV * 2);
    u16* nq    = (u16*)alloc((size_t)SEQ * DQ * 2);
    u16* qcr   = (u16*)alloc((size_t)SEQ * 6144 * 2);
    u16* nkv   = (u16*)alloc((size_t)SEQ * DKV * 2);
    u16* kvb   = (u16*)alloc((size_t)SEQ * 8192 * 2);
    u16* qb    = (u16*)alloc((size_t)NH * SEQ * 192 * 2);
    u16* kb    = (u16*)alloc((size_t)NH * SEQ * 192 * 2);
    u16* vT    = (u16*)alloc((size_t)NH * 128 * SEQ * 2);
    u16* ob    = (u16*)alloc((size_t)SEQ * 4096 * 2);
    float* ct  = (float*)alloc((size_t)SEQ * 32 * 4);
    float* st  = (float*)alloc((size_t)SEQ * 32 * 4);
    (void)in_sizes; (void)n_in; (void)out_size; (void)ws_size;

    // --- prep: rope tables, casts, weight transposes ---
    rope_tab_k<<<(SEQ * 32) / 256, 256, 0, stream>>>(ct, st);
    cast_bf16_k<<<((long)SEQ * HIDDEN) / 1024, 256, 0, stream>>>(hidden, hbf, (long)SEQ * HIDDEN);
    transpose_cast<<<dim3(DQ / 32, HIDDEN / 32), dim3(32, 8), 0, stream>>>(W_dq, WTqkv, HIDDEN, DQ, DQ);
    transpose_cast<<<dim3(DKVP / 32, HIDDEN / 32), dim3(32, 8), 0, stream>>>(
        W_dkv, WTqkv + (size_t)DQ * HIDDEN, HIDDEN, 576, DKVP);
    transpose_cast<<<dim3(6144 / 32, DQ / 32), dim3(32, 8), 0, stream>>>(W_uq, WTuq, DQ, 6144, 6144);
    transpose_cast<<<dim3(8192 / 32, DKV / 32), dim3(32, 8), 0, stream>>>(W_ukv, WTukv, DKV, 8192, 8192);
    transpose_cast<<<dim3(HIDDEN / 32, 4096 / 32), dim3(32, 8), 0, stream>>>(W_o, WTo, 4096, HIDDEN, HIDDEN);

    // --- fused down-projection: cqc = hbf @ [W_dq | W_dkv] (128^2 kernel) ---
    gemm_bt<u16><<<dim3(NQKV / 128, SEQ / 128), 256, 0, stream>>>(
        hbf, WTqkv, cqc, HIDDEN, HIDDEN, HIDDEN, NQKV, 0, 0, 0);
    rmsnorm_k<<<SEQ, 256, 0, stream>>>(cqc, g_q, nq, DQ, NQKV);
    rmsnorm_k<<<SEQ, 256, 0, stream>>>(cqc + DQ, g_kv, nkv, DKV, NQKV);

    // --- up-projections (256^2 deep-pipelined kernel) ---
    gemm256<u16><<<dim3((SEQ / 256) * (6144 / 256)), 512, 0, stream>>>(
        nq, WTuq, qcr, DQ, DQ, DQ, 6144, 6144 / 256);
    gemm256<u16><<<dim3((SEQ / 256) * (8192 / 256)), 512, 0, stream>>>(
        nkv, WTukv, kvb, DKV, DKV, DKV, 8192, 8192 / 256);

    // --- assemble q/k (rope) and vT ---
    build_q_k<<<dim3(SEQ, NH), 192, 0, stream>>>(qcr, qb, ct, st);
    build_k_k<<<dim3(SEQ, NH), 192, 0, stream>>>(kvb, cqc + DQ + DKV, NQKV, kb, ct, st);
    build_vT_k<<<dim3(SEQ / 32, 4, NH), dim3(32, 8), 0, stream>>>(kvb, vT);

    // --- fused flash attention ---
    const float scale = 0.07216878364870322f;  // 1/sqrt(192)
    flash_attn<<<dim3(SEQ / 128, NH), 256, 0, stream>>>(qb, kb, vT, ob, scale);

    // --- output projection (fp32 out, 256^2 kernel) ---
    gemm256<float><<<dim3((SEQ / 256) * (HIDDEN / 256)), 512, 0, stream>>>(
        ob, WTo, out, 4096, 4096, 4096, HIDDEN, HIDDEN / 256);
}

// Round 2
// 849.844 us; speedup vs baseline: 1.1691x; 1.0446x over previous
//
#include <hip/hip_runtime.h>
#include <hip/hip_bf16.h>
#include <math.h>

#define HIDDEN 7168
#define NH 32
#define DQ 1536
#define DKV 512
#define DH 128
#define DR 64
#define SEQ 2048
#define DKVP 640        // DKV+DR=576 padded to multiple of 128
#define NQKV 2176       // DQ + DKVP (fused down-proj width), 17*128
#define SK 4            // split-K factor for the down-projection

typedef unsigned short u16;
typedef __bf16 bf16_t;
typedef bf16_t bf16x8 __attribute__((ext_vector_type(8)));
typedef float f32x4 __attribute__((ext_vector_type(4)));

__device__ __forceinline__ float bf2f(u16 h) {
    union { unsigned u; float f; } q; q.u = ((unsigned)h) << 16; return q.f;
}
__device__ __forceinline__ u16 f2bf(float x) {
    union { float f; unsigned u; } q; q.f = x;
    unsigned r = q.u + 0x7fffu + ((q.u >> 16) & 1u);   // round-to-nearest-even
    return (u16)(r >> 16);
}

// ---------------------------------------------------------------------------
// 128x128 GEMM (down-projection via split-K z-batch: sA/sB = K-offset,
// sC = partial-buffer stride).  C[M,N] = A[M,K](bf16,lda) @ B^T, BT[N,K](ldb).
// ---------------------------------------------------------------------------
template <typename CT>
__global__ __launch_bounds__(256) void gemm_bt(
    const u16* __restrict__ A, const u16* __restrict__ B, CT* __restrict__ C,
    int K, int lda, int ldb, int ldc, long sA, long sB, long sC)
{
    __shared__ u16 As[128 * 32];
    __shared__ u16 Bs[128 * 32];
    A += (long)blockIdx.z * sA;
    B += (long)blockIdx.z * sB;
    C += (long)blockIdx.z * sC;

    const int t = threadIdx.x;
    const int w = t >> 6, lane = t & 63;
    const int lane15 = lane & 15, quad = lane >> 4;
    const int brow = blockIdx.y * 128, bcol = blockIdx.x * 128;
    const int wrow = (w >> 1) * 64, wcol = (w & 1) * 64;

    f32x4 acc[4][4] = {};

    for (int k0 = 0; k0 < K; k0 += 32) {
#pragma unroll
        for (int i = 0; i < 2; ++i) {
            int chunk = i * 256 + t;
            int row = chunk >> 2;
            int kc = (chunk & 3) * 8;
            const u16* ga = A + (long)(brow + row) * lda + k0 + kc;
            const u16* gb = B + (long)(bcol + row) * ldb + k0 + kc;
            u16* la = As + (i * 256 + w * 64) * 8;
            u16* lb = Bs + (i * 256 + w * 64) * 8;
            __builtin_amdgcn_global_load_lds(
                (const __attribute__((address_space(1))) void*)ga,
                (__attribute__((address_space(3))) void*)la, 16, 0, 0);
            __builtin_amdgcn_global_load_lds(
                (const __attribute__((address_space(1))) void*)gb,
                (__attribute__((address_space(3))) void*)lb, 16, 0, 0);
        }
        __syncthreads();

        bf16x8 af[4], bfr[4];
#pragma unroll
        for (int mi = 0; mi < 4; ++mi)
            af[mi] = *(const bf16x8*)(As + (wrow + mi * 16 + lane15) * 32 + quad * 8);
#pragma unroll
        for (int ni = 0; ni < 4; ++ni)
            bfr[ni] = *(const bf16x8*)(Bs + (wcol + ni * 16 + lane15) * 32 + quad * 8);
#pragma unroll
        for (int mi = 0; mi < 4; ++mi)
#pragma unroll
            for (int ni = 0; ni < 4; ++ni)
                acc[mi][ni] = __builtin_amdgcn_mfma_f32_16x16x32_bf16(
                    af[mi], bfr[ni], acc[mi][ni], 0, 0, 0);
        __syncthreads();
    }

#pragma unroll
    for (int mi = 0; mi < 4; ++mi) {
#pragma unroll
        for (int ni = 0; ni < 4; ++ni) {
            int r0 = brow + wrow + mi * 16 + quad * 4;
            int cc = bcol + wcol + ni * 16 + lane15;
#pragma unroll
            for (int r = 0; r < 4; ++r) {
                float v = acc[mi][ni][r];
                if constexpr (sizeof(CT) == 2) C[(long)(r0 + r) * ldc + cc] = f2bf(v);
                else                           C[(long)(r0 + r) * ldc + cc] = v;
            }
        }
    }
}

// sum SK fp32 partials -> bf16.  n multiple of 1024.
__global__ __launch_bounds__(256) void reduce_sk_k(
    const float* __restrict__ part, u16* __restrict__ out, long n, long ps)
{
    long i = ((long)blockIdx.x * 256 + threadIdx.x) * 4;
    if (i >= n) return;
    float4 s0 = *(const float4*)(part + i);
    float4 s1 = *(const float4*)(part + ps + i);
    float4 s2 = *(const float4*)(part + 2 * ps + i);
    float4 s3 = *(const float4*)(part + 3 * ps + i);
    ushort4 o;
    o.x = f2bf(s0.x + s1.x + s2.x + s3.x);
    o.y = f2bf(s0.y + s1.y + s2.y + s3.y);
    o.z = f2bf(s0.z + s1.z + s2.z + s3.z);
    o.w = f2bf(s0.w + s1.w + s2.w + s3.w);
    *(ushort4*)(out + i) = o;
}

// ---------------------------------------------------------------------------
// 256x256 deep-pipelined GEMM, v2: 2 sub-phases per K-step (mid s_barrier
// creates the wave role-split that lets setprio arbitrate; barrier density
// now 1 per 16-K, matching the m201 reference schedule).  BK=32, 8 waves
// (2Mx4N), per-wave 128x64.  LDS ring of 4 K-tile slots = 128 KiB.  Staging
// runs 3 K-tiles ahead, 2 loads issued per sub-phase, counted vmcnt(8) in
// steady state (never 0 mid-loop).  BK=32 -> 64-B LDS rows -> fragment
// ds_read_b128 pattern covers all 8 bank-groups uniformly: conflict-free
// with LINEAR layout (no swizzle needed; rule #21 trivially satisfied).
// Requires: M%256==0, N%256==0, K%32==0, K/32>=4.
// ---------------------------------------------------------------------------
template <typename CT>
__global__ __launch_bounds__(512, 2) void gemm256(
    const u16* __restrict__ A, const u16* __restrict__ B, CT* __restrict__ C,
    int K, int lda, int ldb, int ldc, int nx)
{
    __shared__ u16 lds[4 * 16384];    // 128 KiB: 4 slots of [A 8192 u16][B 8192 u16]
    const int t = threadIdx.x;
    const int lane = t & 63;
    const int w = t >> 6;
    const int lane15 = lane & 15, quad = lane >> 4;
    const int wm = w >> 2, wn = w & 3;            // 2 x 4 wave grid

    // T1: bijective XCD swizzle (nwg % 8 == 0 for all call sites).
    int nwg = gridDim.x, wg = blockIdx.x, tile = wg;
    if ((nwg & 7) == 0) { int q = nwg >> 3; tile = (wg & 7) * q + (wg >> 3); }
    const int bx = tile % nx, by = tile / nx;
    const long brow = (long)by * 256, bcol = (long)bx * 256;

    // Per-thread staging sources: chunk c covers (row = c>>2, k8 = (c&3)*8).
    const u16* gsrc[4];
    int loff[4];
#pragma unroll
    for (int j = 0; j < 2; ++j) {
        int c = j * 512 + t;
        int row = c >> 2, k8 = (c & 3) * 8;
        gsrc[j]     = A + (brow + row) * lda + k8;
        gsrc[j + 2] = B + (bcol + row) * ldb + k8;
        loff[j]     = c * 8;              // u16 units inside slot (A region)
        loff[j + 2] = 8192 + c * 8;       // B region
    }

    const int NT = K >> 5;
    auto stage2 = [&](int tt, int h) {    // 2 x global_load_lds(16B) per thread
        u16* sb = lds + (tt & 3) * 16384;
        int ko = tt * 32;
#pragma unroll
        for (int j = h * 2; j < h * 2 + 2; ++j)
            __builtin_amdgcn_global_load_lds(
                (const __attribute__((address_space(1))) void*)(gsrc[j] + ko),
                (__attribute__((address_space(3))) void*)(sb + loff[j]), 16, 0, 0);
    };

    f32x4 acc[8][4] = {};
    const int aoff = (wm * 128 + lane15) * 32 + quad * 8;
    const int boff = 8192 + (wn * 64 + lane15) * 32 + quad * 8;

    // prime ring: tiles 0,1,2 in flight (12 loads)
    stage2(0, 0); stage2(0, 1);
    stage2(1, 0); stage2(1, 1);
    stage2(2, 0); stage2(2, 1);

    for (int T = 0; T < NT; ++T) {
        // counted wait: tiles T+1,T+2 (8 loads) stay in flight; 0 only at tail
        int rem = NT - 1 - T;
        if (rem >= 2)      asm volatile("s_waitcnt vmcnt(8)" ::: "memory");
        else if (rem == 1) asm volatile("s_waitcnt vmcnt(4)" ::: "memory");
        else               asm volatile("s_waitcnt vmcnt(0)" ::: "memory");
        __builtin_amdgcn_s_barrier();                 // publish tile T
        __builtin_amdgcn_sched_barrier(0);

        const u16* sb = lds + (T & 3) * 16384;
        const bool pf = (T + 3 < NT);

        // ---- sub-phase 1: reads + stage + MFMA half 1 ----
        if (pf) stage2(T + 3, 0);
        bf16x8 bfr[4], af[8];
#pragma unroll
        for (int ni = 0; ni < 4; ++ni)
            bfr[ni] = *(const bf16x8*)(sb + boff + ni * 512);
#pragma unroll
        for (int mi = 0; mi < 4; ++mi)
            af[mi] = *(const bf16x8*)(sb + aoff + mi * 512);
        __builtin_amdgcn_s_setprio(1);
#pragma unroll
        for (int mi = 0; mi < 4; ++mi)
#pragma unroll
            for (int ni = 0; ni < 4; ++ni)
                acc[mi][ni] = __builtin_amdgcn_mfma_f32_16x16x32_bf16(
                    af[mi], bfr[ni], acc[mi][ni], 0, 0, 0);
        __builtin_amdgcn_s_setprio(0);

        __builtin_amdgcn_s_barrier();                 // mid-iter rendezvous
        __builtin_amdgcn_sched_barrier(0);

        // ---- sub-phase 2: reads + stage + MFMA half 2 ----
        if (pf) stage2(T + 3, 1);
#pragma unroll
        for (int mi = 4; mi < 8; ++mi)
            af[mi] = *(const bf16x8*)(sb + aoff + mi * 512);
        __builtin_amdgcn_s_setprio(1);
#pragma unroll
        for (int mi = 4; mi < 8; ++mi)
#pragma unroll
            for (int ni = 0; ni < 4; ++ni)
                acc[mi][ni] = __builtin_amdgcn_mfma_f32_16x16x32_bf16(
                    af[mi], bfr[ni], acc[mi][ni], 0, 0, 0);
        __builtin_amdgcn_s_setprio(0);
        // drain LDS reads before next iter's publish barrier (slot-reuse safety)
        asm volatile("s_waitcnt lgkmcnt(0)" ::: "memory");
        __builtin_amdgcn_sched_barrier(0);
    }

    const long crow0 = brow + wm * 128 + quad * 4;
    const long ccol0 = bcol + wn * 64 + lane15;
#pragma unroll
    for (int mi = 0; mi < 8; ++mi) {
#pragma unroll
        for (int ni = 0; ni < 4; ++ni) {
            long r0 = crow0 + mi * 16;
            long cc = ccol0 + ni * 16;
#pragma unroll
            for (int r = 0; r < 4; ++r) {
                float v = acc[mi][ni][r];
                if constexpr (sizeof(CT) == 2) C[(r0 + r) * ldc + cc] = f2bf(v);
                else                           C[(r0 + r) * ldc + cc] = v;
            }
        }
    }
}

// ---------------------------------------------------------------------------
// Fused flash attention, v2 (transposed-S + register prefetch). Unchanged.
// ---------------------------------------------------------------------------
__global__ __launch_bounds__(256, 2) void flash_attn(
    const u16* __restrict__ qb, const u16* __restrict__ kb,
    const u16* __restrict__ vT, u16* __restrict__ ob, float scale)
{
    __shared__ u16 Ks[64 * 200];      // 25.6 KB
    __shared__ u16 Vs[128 * 72];      // 18.4 KB
    __shared__ u16 Ps[4 * 32 * 72];   // 18.4 KB, wave-private [32 q][72]

    const int t = threadIdx.x;
    const int w = t >> 6, lane = t & 63;
    const int lane15 = lane & 15, quad = lane >> 4;
    const int h = blockIdx.y;
    const int q0 = blockIdx.x * 128 + w * 32;
    u16* Psw = Ps + w * 32 * 72;

    bf16x8 Qf[2][6];
#pragma unroll
    for (int qt = 0; qt < 2; ++qt)
#pragma unroll
        for (int kc = 0; kc < 6; ++kc)
            Qf[qt][kc] = *(const bf16x8*)(
                qb + (long)(h * SEQ + q0 + qt * 16 + lane15) * 192 + kc * 32 + quad * 8);

    f32x4 O[8][2] = {};
    float mst[2] = { -3.0e38f, -3.0e38f }, lst[2] = { 0.f, 0.f };

    bf16x8 Kpf[6], Vpf[4];
    auto load_tiles = [&](int kt) {
#pragma unroll
        for (int i = 0; i < 6; ++i) {
            int chunk = i * 256 + t;
            int row = chunk / 24, c8 = (chunk % 24) * 8;
            Kpf[i] = *(const bf16x8*)(kb + (long)(h * SEQ + kt * 64 + row) * 192 + c8);
        }
#pragma unroll
        for (int i = 0; i < 4; ++i) {
            int chunk = i * 256 + t;
            int dh = chunk >> 3, c8 = (chunk & 7) * 8;
            Vpf[i] = *(const bf16x8*)(vT + (long)(h * 128 + dh) * SEQ + kt * 64 + c8);
        }
    };
    auto store_tiles = [&]() {
#pragma unroll
        for (int i = 0; i < 6; ++i) {
            int chunk = i * 256 + t;
            int row = chunk / 24, c8 = (chunk % 24) * 8;
            *(bf16x8*)(Ks + row * 200 + c8) = Kpf[i];
        }
#pragma unroll
        for (int i = 0; i < 4; ++i) {
            int chunk = i * 256 + t;
            int dh = chunk >> 3, c8 = (chunk & 7) * 8;
            *(bf16x8*)(Vs + dh * 72 + c8) = Vpf[i];
        }
    };

    load_tiles(0);
    store_tiles();
    __syncthreads();

    for (int kt = 0; kt < SEQ / 64; ++kt) {
        load_tiles(kt + 1 < SEQ / 64 ? kt + 1 : kt);

        f32x4 St[4][2] = {};
#pragma unroll
        for (int kc = 0; kc < 6; ++kc) {
            bf16x8 Kf[4];
#pragma unroll
            for (int k4 = 0; k4 < 4; ++k4)
                Kf[k4] = *(const bf16x8*)(Ks + (k4 * 16 + lane15) * 200 + kc * 32 + quad * 8);
#pragma unroll
            for (int k4 = 0; k4 < 4; ++k4)
#pragma unroll
                for (int qt = 0; qt < 2; ++qt)
                    St[k4][qt] = __builtin_amdgcn_mfma_f32_16x16x32_bf16(
                        Kf[k4], Qf[qt][kc], St[k4][qt], 0, 0, 0);
        }

#pragma unroll
        for (int qt = 0; qt < 2; ++qt) {
            float rm = St[0][qt][0];
#pragma unroll
            for (int k4 = 0; k4 < 4; ++k4)
#pragma unroll
                for (int r = 0; r < 4; ++r) rm = fmaxf(rm, St[k4][qt][r]);
            rm = fmaxf(rm, __shfl_xor(rm, 16, 64));
            rm = fmaxf(rm, __shfl_xor(rm, 32, 64));
            rm *= scale;
            float mnew = fmaxf(mst[qt], rm);
            float alpha = __expf(mst[qt] - mnew);
            mst[qt] = mnew;
            float rs = 0.f;
#pragma unroll
            for (int k4 = 0; k4 < 4; ++k4)
#pragma unroll
                for (int r = 0; r < 4; ++r) {
                    float pv = __expf(St[k4][qt][r] * scale - mnew);
                    St[k4][qt][r] = pv; rs += pv;
                }
            rs += __shfl_xor(rs, 16, 64);
            rs += __shfl_xor(rs, 32, 64);
            lst[qt] = lst[qt] * alpha + rs;
#pragma unroll
            for (int dt = 0; dt < 8; ++dt)
#pragma unroll
                for (int r = 0; r < 4; ++r) O[dt][qt][r] *= alpha;
        }

#pragma unroll
        for (int qt = 0; qt < 2; ++qt)
#pragma unroll
            for (int k4 = 0; k4 < 4; ++k4) {
                ushort4 pk;
                pk.x = f2bf(St[k4][qt][0]); pk.y = f2bf(St[k4][qt][1]);
                pk.z = f2bf(St[k4][qt][2]); pk.w = f2bf(St[k4][qt][3]);
                *(ushort4*)(Psw + (qt * 16 + lane15) * 72 + k4 * 16 + quad * 4) = pk;
            }

#pragma unroll
        for (int kc2 = 0; kc2 < 2; ++kc2) {
            bf16x8 Pf[2], Vf[8];
#pragma unroll
            for (int qt = 0; qt < 2; ++qt)
                Pf[qt] = *(const bf16x8*)(Psw + (qt * 16 + lane15) * 72 + kc2 * 32 + quad * 8);
#pragma unroll
            for (int dt = 0; dt < 8; ++dt)
                Vf[dt] = *(const bf16x8*)(Vs + (dt * 16 + lane15) * 72 + kc2 * 32 + quad * 8);
#pragma unroll
            for (int dt = 0; dt < 8; ++dt)
#pragma unroll
                for (int qt = 0; qt < 2; ++qt)
                    O[dt][qt] = __builtin_amdgcn_mfma_f32_16x16x32_bf16(
                        Vf[dt], Pf[qt], O[dt][qt], 0, 0, 0);
        }
        __syncthreads();
        store_tiles();
        __syncthreads();
    }

#pragma unroll
    for (int qt = 0; qt < 2; ++qt) {
        float inv = 1.f / lst[qt];
        int s = q0 + qt * 16 + lane15;
#pragma unroll
        for (int dt = 0; dt < 8; ++dt) {
            ushort4 ov;
            ov.x = f2bf(O[dt][qt][0] * inv); ov.y = f2bf(O[dt][qt][1] * inv);
            ov.z = f2bf(O[dt][qt][2] * inv); ov.w = f2bf(O[dt][qt][3] * inv);
            *(ushort4*)(ob + (long)s * 4096 + h * 128 + dt * 16 + quad * 4) = ov;
        }
    }
}

// ---------------------------------------------------------------------------
__global__ void cast_bf16_k(const float* __restrict__ in, u16* __restrict__ out, long n)
{
    long i = ((long)blockIdx.x * 256 + threadIdx.x) * 4;
    if (i >= n) return;
    float4 v = *(const float4*)(in + i);
    ushort4 o;
    o.x = f2bf(v.x); o.y = f2bf(v.y); o.z = f2bf(v.z); o.w = f2bf(v.w);
    *(ushort4*)(out + i) = o;
}

__global__ void transpose_cast(const float* __restrict__ in, u16* __restrict__ out,
                               int K, int N, int Npad)
{
    __shared__ float tile[32][33];
    int n0 = blockIdx.x * 32, k0 = blockIdx.y * 32;
    int tx = threadIdx.x, ty = threadIdx.y;
#pragma unroll
    for (int i = 0; i < 32; i += 8) {
        int k = k0 + ty + i, n = n0 + tx;
        tile[ty + i][tx] = (n < N) ? in[(long)k * N + n] : 0.f;
    }
    __syncthreads();
#pragma unroll
    for (int i = 0; i < 32; i += 8) {
        int n = n0 + ty + i, k = k0 + tx;
        out[(long)n * K + k] = f2bf(tile[tx][ty + i]);
    }
}

__global__ __launch_bounds__(256) void rmsnorm_k(
    const u16* __restrict__ in, const float* __restrict__ g,
    u16* __restrict__ out, int C, int ldin)
{
    const int row = blockIdx.x;
    const u16* x = in + (long)row * ldin;
    float ss = 0.f;
    for (int c = threadIdx.x; c < C; c += 256) { float v = bf2f(x[c]); ss += v * v; }
#pragma unroll
    for (int off = 32; off; off >>= 1) ss += __shfl_down(ss, off, 64);
    __shared__ float red[4];
    if ((threadIdx.x & 63) == 0) red[threadIdx.x >> 6] = ss;
    __syncthreads();
    float tot = red[0] + red[1] + red[2] + red[3];
    float r = rsqrtf(tot / (float)C + 1.1920929e-07f);
    for (int c = threadIdx.x; c < C; c += 256)
        out[(long)row * C + c] = f2bf(bf2f(x[c]) * r * g[c]);
}

// ---------------------------------------------------------------------------
__global__ void rope_tab_k(float* __restrict__ ct, float* __restrict__ st)
{
    int idx = blockIdx.x * 256 + threadIdx.x;   // SEQ*32 total
    int s = idx >> 5, j = idx & 31;
    float invf = powf(10000.f, -(float)(2 * j) / 64.f);
    float fr = (float)s * invf;
    float sn, cs; sincosf(fr, &sn, &cs);
    ct[idx] = cs; st[idx] = sn;
}

__device__ __forceinline__ float rope_val(const u16* src, int i, int s,
                                          const float* ct, const float* st)
{
    int j = i & 31;
    float cs = ct[s * 32 + j], sn = st[s * 32 + j];
    float x = bf2f(src[i]);
    float xo = (i < 32) ? bf2f(src[i + 32]) : bf2f(src[i - 32]);
    return (i < 32) ? (x * cs - xo * sn) : (x * cs + xo * sn);
}

__global__ void build_q_k(const u16* __restrict__ qcr, u16* __restrict__ q,
                          const float* __restrict__ ct, const float* __restrict__ st)
{
    int s = blockIdx.x, h = blockIdx.y, d = threadIdx.x;
    const u16* src = qcr + ((long)s * NH + h) * 192;
    float val = (d < 128) ? bf2f(src[d]) : rope_val(src + 128, d - 128, s, ct, st);
    q[((long)h * SEQ + s) * 192 + d] = f2bf(val);
}

__global__ void build_k_k(const u16* __restrict__ kv, const u16* __restrict__ ropebuf,
                          int ldrope, u16* __restrict__ kbuf,
                          const float* __restrict__ ct, const float* __restrict__ st)
{
    int s = blockIdx.x, h = blockIdx.y, d = threadIdx.x;
    float val = (d < 128) ? bf2f(kv[(long)s * 8192 + h * 256 + d])
                          : rope_val(ropebuf + (long)s * ldrope, d - 128, s, ct, st);
    kbuf[((long)h * SEQ + s) * 192 + d] = f2bf(val);
}

// vT[NH][128][SEQ] from kv[SEQ][8192] (v = cols h*256+128 .. +255)
__global__ void build_vT_k(const u16* __restrict__ kv, u16* __restrict__ vT)
{
    __shared__ u16 tile[32][33];
    int s0 = blockIdx.x * 32, d0 = blockIdx.y * 32, h = blockIdx.z;
    int tx = threadIdx.x, ty = threadIdx.y;
#pragma unroll
    for (int i = 0; i < 32; i += 8)
        tile[ty + i][tx] = kv[(long)(s0 + ty + i) * 8192 + h * 256 + 128 + d0 + tx];
    __syncthreads();
#pragma unroll
    for (int i = 0; i < 32; i += 8)
        vT[((long)h * 128 + d0 + ty + i) * SEQ + s0 + tx] = tile[tx][ty + i];
}

// ---------------------------------------------------------------------------
extern "C" void kernel_launch(void* const* d_in, const int* in_sizes, int n_in,
                              void* d_out, int out_size, void* d_ws, size_t ws_size,
                              hipStream_t stream)
{
    const float* hidden = (const float*)d_in[0];
    const float* W_dq   = (const float*)d_in[1];
    const float* g_q    = (const float*)d_in[2];
    const float* W_uq   = (const float*)d_in[3];
    const float* W_dkv  = (const float*)d_in[4];
    const float* g_kv   = (const float*)d_in[5];
    const float* W_ukv  = (const float*)d_in[6];
    const float* W_o    = (const float*)d_in[7];
    float* out = (float*)d_out;

    char* p = (char*)d_ws;
    auto alloc = [&](size_t bytes) {
        char* r = p; p += (bytes + 255) & ~(size_t)255; return r;
    };
    u16* hbf   = (u16*)alloc((size_t)SEQ * HIDDEN * 2);
    u16* WTqkv = (u16*)alloc((size_t)NQKV * HIDDEN * 2);
    u16* WTuq  = (u16*)alloc((size_t)6144 * DQ * 2);
    u16* WTukv = (u16*)alloc((size_t)8192 * DKV * 2);
    u16* WTo   = (u16*)alloc((size_t)HIDDEN * 4096 * 2);
    u16* cqc   = (u16*)alloc((size_t)SEQ * NQKV * 2);
    u16* nq    = (u16*)alloc((size_t)SEQ * DQ * 2);
    u16* qcr   = (u16*)alloc((size_t)SEQ * 6144 * 2);
    u16* nkv   = (u16*)alloc((size_t)SEQ * DKV * 2);
    u16* kvb   = (u16*)alloc((size_t)SEQ * 8192 * 2);
    u16* qb    = (u16*)alloc((size_t)NH * SEQ * 192 * 2);
    u16* kb    = (u16*)alloc((size_t)NH * SEQ * 192 * 2);
    u16* vT    = (u16*)alloc((size_t)NH * 128 * SEQ * 2);
    u16* ob    = (u16*)alloc((size_t)SEQ * 4096 * 2);
    float* ct  = (float*)alloc((size_t)SEQ * 32 * 4);
    float* st  = (float*)alloc((size_t)SEQ * 32 * 4);
    (void)in_sizes; (void)n_in; (void)out_size; (void)ws_size;

    // Split-K partials (SK * SEQ * NQKV fp32 = 71.3 MB) overlay the dead
    // qcr..kb region (111 MB, all rewritten after reduce_sk_k completes).
    float* part = (float*)qcr;

    // --- prep: rope tables, casts, weight transposes ---
    rope_tab_k<<<(SEQ * 32) / 256, 256, 0, stream>>>(ct, st);
    cast_bf16_k<<<((long)SEQ * HIDDEN) / 1024, 256, 0, stream>>>(hidden, hbf, (long)SEQ * HIDDEN);
    transpose_cast<<<dim3(DQ / 32, HIDDEN / 32), dim3(32, 8), 0, stream>>>(W_dq, WTqkv, HIDDEN, DQ, DQ);
    transpose_cast<<<dim3(DKVP / 32, HIDDEN / 32), dim3(32, 8), 0, stream>>>(
        W_dkv, WTqkv + (size_t)DQ * HIDDEN, HIDDEN, 576, DKVP);
    transpose_cast<<<dim3(6144 / 32, DQ / 32), dim3(32, 8), 0, stream>>>(W_uq, WTuq, DQ, 6144, 6144);
    transpose_cast<<<dim3(8192 / 32, DKV / 32), dim3(32, 8), 0, stream>>>(W_ukv, WTukv, DKV, 8192, 8192);
    transpose_cast<<<dim3(HIDDEN / 32, 4096 / 32), dim3(32, 8), 0, stream>>>(W_o, WTo, 4096, HIDDEN, HIDDEN);

    // --- fused down-projection, split-K=4: part[z] = hbf @ [W_dq|W_dkv] (K-slice) ---
    gemm_bt<float><<<dim3(NQKV / 128, SEQ / 128, SK), 256, 0, stream>>>(
        hbf, WTqkv, part, HIDDEN / SK, HIDDEN, HIDDEN, NQKV,
        HIDDEN / SK, HIDDEN / SK, (long)SEQ * NQKV);
    reduce_sk_k<<<((long)SEQ * NQKV) / 1024, 256, 0, stream>>>(
        part, cqc, (long)SEQ * NQKV, (long)SEQ * NQKV);

    rmsnorm_k<<<SEQ, 256, 0, stream>>>(cqc, g_q, nq, DQ, NQKV);
    rmsnorm_k<<<SEQ, 256, 0, stream>>>(cqc + DQ, g_kv, nkv, DKV, NQKV);

    // --- up-projections (256^2 deep-pipelined kernel, v2) ---
    gemm256<u16><<<dim3((SEQ / 256) * (6144 / 256)), 512, 0, stream>>>(
        nq, WTuq, qcr, DQ, DQ, DQ, 6144, 6144 / 256);
    gemm256<u16><<<dim3((SEQ / 256) * (8192 / 256)), 512, 0, stream>>>(
        nkv, WTukv, kvb, DKV, DKV, DKV, 8192, 8192 / 256);

    // --- assemble q/k (rope) and vT ---
    build_q_k<<<dim3(SEQ, NH), 192, 0, stream>>>(qcr, qb, ct, st);
    build_k_k<<<dim3(SEQ, NH), 192, 0, stream>>>(kvb, cqc + DQ + DKV, NQKV, kb, ct, st);
    build_vT_k<<<dim3(SEQ / 32, 4, NH), dim3(32, 8), 0, stream>>>(kvb, vT);

    // --- fused flash attention ---
    const float scale = 0.07216878364870322f;  // 1/sqrt(192)
    flash_attn<<<dim3(SEQ / 128, NH), 256, 0, stream>>>(qb, kb, vT, ob, scale);

    // --- output projection (fp32 out, 256^2 kernel) ---
    gemm256<float><<<dim3((SEQ / 256) * (HIDDEN / 256)), 512, 0, stream>>>(
        ob, WTo, out, 4096, 4096, 4096, HIDDEN, HIDDEN / 256);
}

// Round 3
// 836.751 us; speedup vs baseline: 1.1874x; 1.0156x over previous
//
#include <hip/hip_runtime.h>
#include <hip/hip_bf16.h>
#include <math.h>

#define HIDDEN 7168
#define NH 32
#define DQ 1536
#define DKV 512
#define DH 128
#define DR 64
#define SEQ 2048
#define DKVP 640        // DKV+DR=576 padded to multiple of 128
#define NQKV 2176       // DQ + DKVP (fused down-proj width), 17*128
#define SK 4            // split-K factor for the down-projection

typedef unsigned short u16;
typedef __bf16 bf16_t;
typedef bf16_t bf16x8 __attribute__((ext_vector_type(8)));
typedef float f32x4 __attribute__((ext_vector_type(4)));

__device__ __forceinline__ float bf2f(u16 h) {
    union { unsigned u; float f; } q; q.u = ((unsigned)h) << 16; return q.f;
}
__device__ __forceinline__ u16 f2bf(float x) {
    union { float f; unsigned u; } q; q.f = x;
    unsigned r = q.u + 0x7fffu + ((q.u >> 16) & 1u);   // round-to-nearest-even
    return (u16)(r >> 16);
}

// ---------------------------------------------------------------------------
// 128x128 GEMM (split-K z-batch: sA/sB = K-offset, sC = partial stride).
// C[M,N] = A[M,K](bf16,lda) @ B^T, BT[N,K](ldb).
// T2 swizzle: LDS rows are 64 B (4 x 16B quads).  Fragment reads hit
// bank-group (quad + 4*(row&1))%8; 8 consecutive rows at fixed quad = 4-way
// conflict.  Fix: quad' = quad ^ ((row>>1)&3) -> groups {0..7} all distinct.
// Applied both-sides: linear LDS dest (global_load_lds req), pre-swizzled
// GLOBAL source column, same XOR on the read (rule #21 involution).
// Read-side XOR == ((lane15>>1)&3) since row%16==lane15 in 16-aligned tiles.
// ---------------------------------------------------------------------------
template <typename CT>
__global__ __launch_bounds__(256) void gemm_bt(
    const u16* __restrict__ A, const u16* __restrict__ B, CT* __restrict__ C,
    int K, int lda, int ldb, int ldc, long sA, long sB, long sC)
{
    __shared__ u16 As[128 * 32];
    __shared__ u16 Bs[128 * 32];
    A += (long)blockIdx.z * sA;
    B += (long)blockIdx.z * sB;
    C += (long)blockIdx.z * sC;

    const int t = threadIdx.x;
    const int w = t >> 6, lane = t & 63;
    const int lane15 = lane & 15, quad = lane >> 4;
    const int brow = blockIdx.y * 128, bcol = blockIdx.x * 128;
    const int wrow = (w >> 1) * 64, wcol = (w & 1) * 64;
    const int axor = ((lane15 >> 1) & 3) * 8;    // read-side XOR (u16 units)

    f32x4 acc[4][4] = {};

    for (int k0 = 0; k0 < K; k0 += 32) {
#pragma unroll
        for (int i = 0; i < 2; ++i) {
            int chunk = i * 256 + t;
            int row = chunk >> 2;
            int kc = ((chunk & 3) ^ ((row >> 1) & 3)) * 8;   // source pre-swizzle
            const u16* ga = A + (long)(brow + row) * lda + k0 + kc;
            const u16* gb = B + (long)(bcol + row) * ldb + k0 + kc;
            u16* la = As + (i * 256 + w * 64) * 8;           // linear dest
            u16* lb = Bs + (i * 256 + w * 64) * 8;
            __builtin_amdgcn_global_load_lds(
                (const __attribute__((address_space(1))) void*)ga,
                (__attribute__((address_space(3))) void*)la, 16, 0, 0);
            __builtin_amdgcn_global_load_lds(
                (const __attribute__((address_space(1))) void*)gb,
                (__attribute__((address_space(3))) void*)lb, 16, 0, 0);
        }
        __syncthreads();

        bf16x8 af[4], bfr[4];
#pragma unroll
        for (int mi = 0; mi < 4; ++mi)
            af[mi] = *(const bf16x8*)(As + (wrow + mi * 16 + lane15) * 32 + (quad * 8 ^ axor));
#pragma unroll
        for (int ni = 0; ni < 4; ++ni)
            bfr[ni] = *(const bf16x8*)(Bs + (wcol + ni * 16 + lane15) * 32 + (quad * 8 ^ axor));
#pragma unroll
        for (int mi = 0; mi < 4; ++mi)
#pragma unroll
            for (int ni = 0; ni < 4; ++ni)
                acc[mi][ni] = __builtin_amdgcn_mfma_f32_16x16x32_bf16(
                    af[mi], bfr[ni], acc[mi][ni], 0, 0, 0);
        __syncthreads();
    }

#pragma unroll
    for (int mi = 0; mi < 4; ++mi) {
#pragma unroll
        for (int ni = 0; ni < 4; ++ni) {
            int r0 = brow + wrow + mi * 16 + quad * 4;
            int cc = bcol + wcol + ni * 16 + lane15;
#pragma unroll
            for (int r = 0; r < 4; ++r) {
                float v = acc[mi][ni][r];
                if constexpr (sizeof(CT) == 2) C[(long)(r0 + r) * ldc + cc] = f2bf(v);
                else                           C[(long)(r0 + r) * ldc + cc] = v;
            }
        }
    }
}

// sum SK fp32 partials -> bf16.  n multiple of 1024.
__global__ __launch_bounds__(256) void reduce_sk_k(
    const float* __restrict__ part, u16* __restrict__ out, long n, long ps)
{
    long i = ((long)blockIdx.x * 256 + threadIdx.x) * 4;
    if (i >= n) return;
    float4 s0 = *(const float4*)(part + i);
    float4 s1 = *(const float4*)(part + ps + i);
    float4 s2 = *(const float4*)(part + 2 * ps + i);
    float4 s3 = *(const float4*)(part + 3 * ps + i);
    ushort4 o;
    o.x = f2bf(s0.x + s1.x + s2.x + s3.x);
    o.y = f2bf(s0.y + s1.y + s2.y + s3.y);
    o.z = f2bf(s0.z + s1.z + s2.z + s3.z);
    o.w = f2bf(s0.w + s1.w + s2.w + s3.w);
    *(ushort4*)(out + i) = o;
}

// ---------------------------------------------------------------------------
// 256x256 deep-pipelined GEMM, v3: v2 + T2 bank-swizzle (same scheme as
// gemm_bt above; read XOR is the per-lane constant ((lane15>>1)&3)*8 folded
// into aoff/boff — zero loop cost).  2 sub-phases per K-step, counted
// vmcnt(8) ring of 4 K-tile slots, 3-ahead prefetch, setprio around MFMA.
// Requires: M%256==0, N%256==0, K%32==0, K/32>=4.
// ---------------------------------------------------------------------------
template <typename CT>
__global__ __launch_bounds__(512, 2) void gemm256(
    const u16* __restrict__ A, const u16* __restrict__ B, CT* __restrict__ C,
    int K, int lda, int ldb, int ldc, int nx)
{
    __shared__ u16 lds[4 * 16384];    // 128 KiB: 4 slots of [A 8192 u16][B 8192 u16]
    const int t = threadIdx.x;
    const int lane = t & 63;
    const int w = t >> 6;
    const int lane15 = lane & 15, quad = lane >> 4;
    const int wm = w >> 2, wn = w & 3;            // 2 x 4 wave grid

    // T1: bijective XCD swizzle (nwg % 8 == 0 for all call sites).
    int nwg = gridDim.x, wg = blockIdx.x, tile = wg;
    if ((nwg & 7) == 0) { int q = nwg >> 3; tile = (wg & 7) * q + (wg >> 3); }
    const int bx = tile % nx, by = tile / nx;
    const long brow = (long)by * 256, bcol = (long)bx * 256;

    // Per-thread staging sources: chunk c covers (row = c>>2, quad = c&3).
    // T2: source column pre-swizzled so linear LDS dest holds swizzled layout.
    const u16* gsrc[4];
    int loff[4];
#pragma unroll
    for (int j = 0; j < 2; ++j) {
        int c = j * 512 + t;
        int row = c >> 2;
        int k8 = ((c & 3) ^ ((row >> 1) & 3)) * 8;
        gsrc[j]     = A + (brow + row) * lda + k8;
        gsrc[j + 2] = B + (bcol + row) * ldb + k8;
        loff[j]     = c * 8;              // u16 units inside slot (A region)
        loff[j + 2] = 8192 + c * 8;       // B region
    }

    const int NT = K >> 5;
    auto stage2 = [&](int tt, int h) {    // 2 x global_load_lds(16B) per thread
        u16* sb = lds + (tt & 3) * 16384;
        int ko = tt * 32;
#pragma unroll
        for (int j = h * 2; j < h * 2 + 2; ++j)
            __builtin_amdgcn_global_load_lds(
                (const __attribute__((address_space(1))) void*)(gsrc[j] + ko),
                (__attribute__((address_space(3))) void*)(sb + loff[j]), 16, 0, 0);
    };

    f32x4 acc[8][4] = {};
    const int axor = ((lane15 >> 1) & 3) * 8;    // read-side XOR (u16 units)
    const int aoff = (wm * 128 + lane15) * 32 + (quad * 8 ^ axor);
    const int boff = 8192 + (wn * 64 + lane15) * 32 + (quad * 8 ^ axor);

    // prime ring: tiles 0,1,2 in flight (12 loads)
    stage2(0, 0); stage2(0, 1);
    stage2(1, 0); stage2(1, 1);
    stage2(2, 0); stage2(2, 1);

    for (int T = 0; T < NT; ++T) {
        // counted wait: tiles T+1,T+2 (8 loads) stay in flight; 0 only at tail
        int rem = NT - 1 - T;
        if (rem >= 2)      asm volatile("s_waitcnt vmcnt(8)" ::: "memory");
        else if (rem == 1) asm volatile("s_waitcnt vmcnt(4)" ::: "memory");
        else               asm volatile("s_waitcnt vmcnt(0)" ::: "memory");
        __builtin_amdgcn_s_barrier();                 // publish tile T
        __builtin_amdgcn_sched_barrier(0);

        const u16* sb = lds + (T & 3) * 16384;
        const bool pf = (T + 3 < NT);

        // ---- sub-phase 1: reads + stage + MFMA half 1 ----
        if (pf) stage2(T + 3, 0);
        bf16x8 bfr[4], af[8];
#pragma unroll
        for (int ni = 0; ni < 4; ++ni)
            bfr[ni] = *(const bf16x8*)(sb + boff + ni * 512);
#pragma unroll
        for (int mi = 0; mi < 4; ++mi)
            af[mi] = *(const bf16x8*)(sb + aoff + mi * 512);
        __builtin_amdgcn_s_setprio(1);
#pragma unroll
        for (int mi = 0; mi < 4; ++mi)
#pragma unroll
            for (int ni = 0; ni < 4; ++ni)
                acc[mi][ni] = __builtin_amdgcn_mfma_f32_16x16x32_bf16(
                    af[mi], bfr[ni], acc[mi][ni], 0, 0, 0);
        __builtin_amdgcn_s_setprio(0);

        __builtin_amdgcn_s_barrier();                 // mid-iter rendezvous
        __builtin_amdgcn_sched_barrier(0);

        // ---- sub-phase 2: reads + stage + MFMA half 2 ----
        if (pf) stage2(T + 3, 1);
#pragma unroll
        for (int mi = 4; mi < 8; ++mi)
            af[mi] = *(const bf16x8*)(sb + aoff + mi * 512);
        __builtin_amdgcn_s_setprio(1);
#pragma unroll
        for (int mi = 4; mi < 8; ++mi)
#pragma unroll
            for (int ni = 0; ni < 4; ++ni)
                acc[mi][ni] = __builtin_amdgcn_mfma_f32_16x16x32_bf16(
                    af[mi], bfr[ni], acc[mi][ni], 0, 0, 0);
        __builtin_amdgcn_s_setprio(0);
        // drain LDS reads before next iter's publish barrier (slot-reuse safety)
        asm volatile("s_waitcnt lgkmcnt(0)" ::: "memory");
        __builtin_amdgcn_sched_barrier(0);
    }

    const long crow0 = brow + wm * 128 + quad * 4;
    const long ccol0 = bcol + wn * 64 + lane15;
#pragma unroll
    for (int mi = 0; mi < 8; ++mi) {
#pragma unroll
        for (int ni = 0; ni < 4; ++ni) {
            long r0 = crow0 + mi * 16;
            long cc = ccol0 + ni * 16;
#pragma unroll
            for (int r = 0; r < 4; ++r) {
                float v = acc[mi][ni][r];
                if constexpr (sizeof(CT) == 2) C[(r0 + r) * ldc + cc] = f2bf(v);
                else                           C[(r0 + r) * ldc + cc] = v;
            }
        }
    }
}

// ---------------------------------------------------------------------------
// Fused flash attention, v2 (transposed-S + register prefetch). Unchanged.
// ---------------------------------------------------------------------------
__global__ __launch_bounds__(256, 2) void flash_attn(
    const u16* __restrict__ qb, const u16* __restrict__ kb,
    const u16* __restrict__ vT, u16* __restrict__ ob, float scale)
{
    __shared__ u16 Ks[64 * 200];      // 25.6 KB
    __shared__ u16 Vs[128 * 72];      // 18.4 KB
    __shared__ u16 Ps[4 * 32 * 72];   // 18.4 KB, wave-private [32 q][72]

    const int t = threadIdx.x;
    const int w = t >> 6, lane = t & 63;
    const int lane15 = lane & 15, quad = lane >> 4;
    const int h = blockIdx.y;
    const int q0 = blockIdx.x * 128 + w * 32;
    u16* Psw = Ps + w * 32 * 72;

    bf16x8 Qf[2][6];
#pragma unroll
    for (int qt = 0; qt < 2; ++qt)
#pragma unroll
        for (int kc = 0; kc < 6; ++kc)
            Qf[qt][kc] = *(const bf16x8*)(
                qb + (long)(h * SEQ + q0 + qt * 16 + lane15) * 192 + kc * 32 + quad * 8);

    f32x4 O[8][2] = {};
    float mst[2] = { -3.0e38f, -3.0e38f }, lst[2] = { 0.f, 0.f };

    bf16x8 Kpf[6], Vpf[4];
    auto load_tiles = [&](int kt) {
#pragma unroll
        for (int i = 0; i < 6; ++i) {
            int chunk = i * 256 + t;
            int row = chunk / 24, c8 = (chunk % 24) * 8;
            Kpf[i] = *(const bf16x8*)(kb + (long)(h * SEQ + kt * 64 + row) * 192 + c8);
        }
#pragma unroll
        for (int i = 0; i < 4; ++i) {
            int chunk = i * 256 + t;
            int dh = chunk >> 3, c8 = (chunk & 7) * 8;
            Vpf[i] = *(const bf16x8*)(vT + (long)(h * 128 + dh) * SEQ + kt * 64 + c8);
        }
    };
    auto store_tiles = [&]() {
#pragma unroll
        for (int i = 0; i < 6; ++i) {
            int chunk = i * 256 + t;
            int row = chunk / 24, c8 = (chunk % 24) * 8;
            *(bf16x8*)(Ks + row * 200 + c8) = Kpf[i];
        }
#pragma unroll
        for (int i = 0; i < 4; ++i) {
            int chunk = i * 256 + t;
            int dh = chunk >> 3, c8 = (chunk & 7) * 8;
            *(bf16x8*)(Vs + dh * 72 + c8) = Vpf[i];
        }
    };

    load_tiles(0);
    store_tiles();
    __syncthreads();

    for (int kt = 0; kt < SEQ / 64; ++kt) {
        load_tiles(kt + 1 < SEQ / 64 ? kt + 1 : kt);

        f32x4 St[4][2] = {};
#pragma unroll
        for (int kc = 0; kc < 6; ++kc) {
            bf16x8 Kf[4];
#pragma unroll
            for (int k4 = 0; k4 < 4; ++k4)
                Kf[k4] = *(const bf16x8*)(Ks + (k4 * 16 + lane15) * 200 + kc * 32 + quad * 8);
#pragma unroll
            for (int k4 = 0; k4 < 4; ++k4)
#pragma unroll
                for (int qt = 0; qt < 2; ++qt)
                    St[k4][qt] = __builtin_amdgcn_mfma_f32_16x16x32_bf16(
                        Kf[k4], Qf[qt][kc], St[k4][qt], 0, 0, 0);
        }

#pragma unroll
        for (int qt = 0; qt < 2; ++qt) {
            float rm = St[0][qt][0];
#pragma unroll
            for (int k4 = 0; k4 < 4; ++k4)
#pragma unroll
                for (int r = 0; r < 4; ++r) rm = fmaxf(rm, St[k4][qt][r]);
            rm = fmaxf(rm, __shfl_xor(rm, 16, 64));
            rm = fmaxf(rm, __shfl_xor(rm, 32, 64));
            rm *= scale;
            float mnew = fmaxf(mst[qt], rm);
            float alpha = __expf(mst[qt] - mnew);
            mst[qt] = mnew;
            float rs = 0.f;
#pragma unroll
            for (int k4 = 0; k4 < 4; ++k4)
#pragma unroll
                for (int r = 0; r < 4; ++r) {
                    float pv = __expf(St[k4][qt][r] * scale - mnew);
                    St[k4][qt][r] = pv; rs += pv;
                }
            rs += __shfl_xor(rs, 16, 64);
            rs += __shfl_xor(rs, 32, 64);
            lst[qt] = lst[qt] * alpha + rs;
#pragma unroll
            for (int dt = 0; dt < 8; ++dt)
#pragma unroll
                for (int r = 0; r < 4; ++r) O[dt][qt][r] *= alpha;
        }

#pragma unroll
        for (int qt = 0; qt < 2; ++qt)
#pragma unroll
            for (int k4 = 0; k4 < 4; ++k4) {
                ushort4 pk;
                pk.x = f2bf(St[k4][qt][0]); pk.y = f2bf(St[k4][qt][1]);
                pk.z = f2bf(St[k4][qt][2]); pk.w = f2bf(St[k4][qt][3]);
                *(ushort4*)(Psw + (qt * 16 + lane15) * 72 + k4 * 16 + quad * 4) = pk;
            }

#pragma unroll
        for (int kc2 = 0; kc2 < 2; ++kc2) {
            bf16x8 Pf[2], Vf[8];
#pragma unroll
            for (int qt = 0; qt < 2; ++qt)
                Pf[qt] = *(const bf16x8*)(Psw + (qt * 16 + lane15) * 72 + kc2 * 32 + quad * 8);
#pragma unroll
            for (int dt = 0; dt < 8; ++dt)
                Vf[dt] = *(const bf16x8*)(Vs + (dt * 16 + lane15) * 72 + kc2 * 32 + quad * 8);
#pragma unroll
            for (int dt = 0; dt < 8; ++dt)
#pragma unroll
                for (int qt = 0; qt < 2; ++qt)
                    O[dt][qt] = __builtin_amdgcn_mfma_f32_16x16x32_bf16(
                        Vf[dt], Pf[qt], O[dt][qt], 0, 0, 0);
        }
        __syncthreads();
        store_tiles();
        __syncthreads();
    }

#pragma unroll
    for (int qt = 0; qt < 2; ++qt) {
        float inv = 1.f / lst[qt];
        int s = q0 + qt * 16 + lane15;
#pragma unroll
        for (int dt = 0; dt < 8; ++dt) {
            ushort4 ov;
            ov.x = f2bf(O[dt][qt][0] * inv); ov.y = f2bf(O[dt][qt][1] * inv);
            ov.z = f2bf(O[dt][qt][2] * inv); ov.w = f2bf(O[dt][qt][3] * inv);
            *(ushort4*)(ob + (long)s * 4096 + h * 128 + dt * 16 + quad * 4) = ov;
        }
    }
}

// ---------------------------------------------------------------------------
__global__ void cast_bf16_k(const float* __restrict__ in, u16* __restrict__ out, long n)
{
    long i = ((long)blockIdx.x * 256 + threadIdx.x) * 4;
    if (i >= n) return;
    float4 v = *(const float4*)(in + i);
    ushort4 o;
    o.x = f2bf(v.x); o.y = f2bf(v.y); o.z = f2bf(v.z); o.w = f2bf(v.w);
    *(ushort4*)(out + i) = o;
}

__global__ void transpose_cast(const float* __restrict__ in, u16* __restrict__ out,
                               int K, int N, int Npad)
{
    __shared__ float tile[32][33];
    int n0 = blockIdx.x * 32, k0 = blockIdx.y * 32;
    int tx = threadIdx.x, ty = threadIdx.y;
#pragma unroll
    for (int i = 0; i < 32; i += 8) {
        int k = k0 + ty + i, n = n0 + tx;
        tile[ty + i][tx] = (n < N) ? in[(long)k * N + n] : 0.f;
    }
    __syncthreads();
#pragma unroll
    for (int i = 0; i < 32; i += 8) {
        int n = n0 + ty + i, k = k0 + tx;
        out[(long)n * K + k] = f2bf(tile[tx][ty + i]);
    }
}

__global__ __launch_bounds__(256) void rmsnorm_k(
    const u16* __restrict__ in, const float* __restrict__ g,
    u16* __restrict__ out, int C, int ldin)
{
    const int row = blockIdx.x;
    const u16* x = in + (long)row * ldin;
    float ss = 0.f;
    for (int c = threadIdx.x; c < C; c += 256) { float v = bf2f(x[c]); ss += v * v; }
#pragma unroll
    for (int off = 32; off; off >>= 1) ss += __shfl_down(ss, off, 64);
    __shared__ float red[4];
    if ((threadIdx.x & 63) == 0) red[threadIdx.x >> 6] = ss;
    __syncthreads();
    float tot = red[0] + red[1] + red[2] + red[3];
    float r = rsqrtf(tot / (float)C + 1.1920929e-07f);
    for (int c = threadIdx.x; c < C; c += 256)
        out[(long)row * C + c] = f2bf(bf2f(x[c]) * r * g[c]);
}

// ---------------------------------------------------------------------------
__global__ void rope_tab_k(float* __restrict__ ct, float* __restrict__ st)
{
    int idx = blockIdx.x * 256 + threadIdx.x;   // SEQ*32 total
    int s = idx >> 5, j = idx & 31;
    float invf = powf(10000.f, -(float)(2 * j) / 64.f);
    float fr = (float)s * invf;
    float sn, cs; sincosf(fr, &sn, &cs);
    ct[idx] = cs; st[idx] = sn;
}

__device__ __forceinline__ float rope_val(const u16* src, int i, int s,
                                          const float* ct, const float* st)
{
    int j = i & 31;
    float cs = ct[s * 32 + j], sn = st[s * 32 + j];
    float x = bf2f(src[i]);
    float xo = (i < 32) ? bf2f(src[i + 32]) : bf2f(src[i - 32]);
    return (i < 32) ? (x * cs - xo * sn) : (x * cs + xo * sn);
}

__global__ void build_q_k(const u16* __restrict__ qcr, u16* __restrict__ q,
                          const float* __restrict__ ct, const float* __restrict__ st)
{
    int s = blockIdx.x, h = blockIdx.y, d = threadIdx.x;
    const u16* src = qcr + ((long)s * NH + h) * 192;
    float val = (d < 128) ? bf2f(src[d]) : rope_val(src + 128, d - 128, s, ct, st);
    q[((long)h * SEQ + s) * 192 + d] = f2bf(val);
}

__global__ void build_k_k(const u16* __restrict__ kv, const u16* __restrict__ ropebuf,
                          int ldrope, u16* __restrict__ kbuf,
                          const float* __restrict__ ct, const float* __restrict__ st)
{
    int s = blockIdx.x, h = blockIdx.y, d = threadIdx.x;
    float val = (d < 128) ? bf2f(kv[(long)s * 8192 + h * 256 + d])
                          : rope_val(ropebuf + (long)s * ldrope, d - 128, s, ct, st);
    kbuf[((long)h * SEQ + s) * 192 + d] = f2bf(val);
}

// vT[NH][128][SEQ] from kv[SEQ][8192] (v = cols h*256+128 .. +255)
__global__ void build_vT_k(const u16* __restrict__ kv, u16* __restrict__ vT)
{
    __shared__ u16 tile[32][33];
    int s0 = blockIdx.x * 32, d0 = blockIdx.y * 32, h = blockIdx.z;
    int tx = threadIdx.x, ty = threadIdx.y;
#pragma unroll
    for (int i = 0; i < 32; i += 8)
        tile[ty + i][tx] = kv[(long)(s0 + ty + i) * 8192 + h * 256 + 128 + d0 + tx];
    __syncthreads();
#pragma unroll
    for (int i = 0; i < 32; i += 8)
        vT[((long)h * 128 + d0 + ty + i) * SEQ + s0 + tx] = tile[tx][ty + i];
}

// ---------------------------------------------------------------------------
extern "C" void kernel_launch(void* const* d_in, const int* in_sizes, int n_in,
                              void* d_out, int out_size, void* d_ws, size_t ws_size,
                              hipStream_t stream)
{
    const float* hidden = (const float*)d_in[0];
    const float* W_dq   = (const float*)d_in[1];
    const float* g_q    = (const float*)d_in[2];
    const float* W_uq   = (const float*)d_in[3];
    const float* W_dkv  = (const float*)d_in[4];
    const float* g_kv   = (const float*)d_in[5];
    const float* W_ukv  = (const float*)d_in[6];
    const float* W_o    = (const float*)d_in[7];
    float* out = (float*)d_out;

    char* p = (char*)d_ws;
    auto alloc = [&](size_t bytes) {
        char* r = p; p += (bytes + 255) & ~(size_t)255; return r;
    };
    u16* hbf   = (u16*)alloc((size_t)SEQ * HIDDEN * 2);
    u16* WTqkv = (u16*)alloc((size_t)NQKV * HIDDEN * 2);
    u16* WTuq  = (u16*)alloc((size_t)6144 * DQ * 2);
    u16* WTukv = (u16*)alloc((size_t)8192 * DKV * 2);
    u16* WTo   = (u16*)alloc((size_t)HIDDEN * 4096 * 2);
    u16* cqc   = (u16*)alloc((size_t)SEQ * NQKV * 2);
    u16* nq    = (u16*)alloc((size_t)SEQ * DQ * 2);
    u16* qcr   = (u16*)alloc((size_t)SEQ * 6144 * 2);
    u16* nkv   = (u16*)alloc((size_t)SEQ * DKV * 2);
    u16* kvb   = (u16*)alloc((size_t)SEQ * 8192 * 2);
    u16* qb    = (u16*)alloc((size_t)NH * SEQ * 192 * 2);
    u16* kb    = (u16*)alloc((size_t)NH * SEQ * 192 * 2);
    u16* vT    = (u16*)alloc((size_t)NH * 128 * SEQ * 2);
    u16* ob    = (u16*)alloc((size_t)SEQ * 4096 * 2);
    float* ct  = (float*)alloc((size_t)SEQ * 32 * 4);
    float* st  = (float*)alloc((size_t)SEQ * 32 * 4);
    (void)in_sizes; (void)n_in; (void)out_size; (void)ws_size;

    // Split-K partials (SK * SEQ * NQKV fp32 = 71.3 MB) overlay the dead
    // qcr..kb region (111 MB, all rewritten after reduce_sk_k completes).
    float* part = (float*)qcr;

    // --- prep: rope tables, casts, weight transposes ---
    rope_tab_k<<<(SEQ * 32) / 256, 256, 0, stream>>>(ct, st);
    cast_bf16_k<<<((long)SEQ * HIDDEN) / 1024, 256, 0, stream>>>(hidden, hbf, (long)SEQ * HIDDEN);
    transpose_cast<<<dim3(DQ / 32, HIDDEN / 32), dim3(32, 8), 0, stream>>>(W_dq, WTqkv, HIDDEN, DQ, DQ);
    transpose_cast<<<dim3(DKVP / 32, HIDDEN / 32), dim3(32, 8), 0, stream>>>(
        W_dkv, WTqkv + (size_t)DQ * HIDDEN, HIDDEN, 576, DKVP);
    transpose_cast<<<dim3(6144 / 32, DQ / 32), dim3(32, 8), 0, stream>>>(W_uq, WTuq, DQ, 6144, 6144);
    transpose_cast<<<dim3(8192 / 32, DKV / 32), dim3(32, 8), 0, stream>>>(W_ukv, WTukv, DKV, 8192, 8192);
    transpose_cast<<<dim3(HIDDEN / 32, 4096 / 32), dim3(32, 8), 0, stream>>>(W_o, WTo, 4096, HIDDEN, HIDDEN);

    // --- fused down-projection, split-K=4: part[z] = hbf @ [W_dq|W_dkv] (K-slice) ---
    gemm_bt<float><<<dim3(NQKV / 128, SEQ / 128, SK), 256, 0, stream>>>(
        hbf, WTqkv, part, HIDDEN / SK, HIDDEN, HIDDEN, NQKV,
        HIDDEN / SK, HIDDEN / SK, (long)SEQ * NQKV);
    reduce_sk_k<<<((long)SEQ * NQKV) / 1024, 256, 0, stream>>>(
        part, cqc, (long)SEQ * NQKV, (long)SEQ * NQKV);

    rmsnorm_k<<<SEQ, 256, 0, stream>>>(cqc, g_q, nq, DQ, NQKV);
    rmsnorm_k<<<SEQ, 256, 0, stream>>>(cqc + DQ, g_kv, nkv, DKV, NQKV);

    // --- up-projections (256^2 deep-pipelined kernel, v3) ---
    gemm256<u16><<<dim3((SEQ / 256) * (6144 / 256)), 512, 0, stream>>>(
        nq, WTuq, qcr, DQ, DQ, DQ, 6144, 6144 / 256);
    gemm256<u16><<<dim3((SEQ / 256) * (8192 / 256)), 512, 0, stream>>>(
        nkv, WTukv, kvb, DKV, DKV, DKV, 8192, 8192 / 256);

    // --- assemble q/k (rope) and vT ---
    build_q_k<<<dim3(SEQ, NH), 192, 0, stream>>>(qcr, qb, ct, st);
    build_k_k<<<dim3(SEQ, NH), 192, 0, stream>>>(kvb, cqc + DQ + DKV, NQKV, kb, ct, st);
    build_vT_k<<<dim3(SEQ / 32, 4, NH), dim3(32, 8), 0, stream>>>(kvb, vT);

    // --- fused flash attention ---
    const float scale = 0.07216878364870322f;  // 1/sqrt(192)
    flash_attn<<<dim3(SEQ / 128, NH), 256, 0, stream>>>(qb, kb, vT, ob, scale);

    // --- output projection (fp32 out, 256^2 kernel) ---
    gemm256<float><<<dim3((SEQ / 256) * (HIDDEN / 256)), 512, 0, stream>>>(
        ob, WTo, out, 4096, 4096, 4096, HIDDEN, HIDDEN / 256);
}